// Round 9
// baseline (1373.444 us; speedup 1.0000x reference)
//
#include <hip/hip_runtime.h>
#include <math.h>

#define NN 100000
#define NE 1600000
#define DD 32
#define CC 16
#define SCAN_B 391  // ceil(NN/256)

typedef unsigned short bf16_t;
typedef __attribute__((ext_vector_type(8))) short short8v;
typedef __attribute__((ext_vector_type(4))) float float4v;

static inline unsigned gblocks(long total) { return (unsigned)((total + 255) / 256); }

__device__ inline bf16_t f2bf(float f) {
    unsigned u = __float_as_uint(f);
    u += 0x7fffu + ((u >> 16) & 1u);
    return (bf16_t)(u >> 16);
}
__device__ inline float bf2f(bf16_t h) { return __uint_as_float(((unsigned)h) << 16); }
__device__ inline unsigned pk2(float a, float b) {
    return (unsigned)f2bf(a) | ((unsigned)f2bf(b) << 16);
}

__global__ void zero_k(float* p, long n) {
    long i = (long)blockIdx.x * 256 + threadIdx.x;
    if (i < n) p[i] = 0.f;
}

__global__ void zero_int_k(int* p, int n) {
    int i = blockIdx.x * 256 + threadIdx.x;
    if (i < n) p[i] = 0;
}

// ---------------- CSR build (proven in round 4) ----------------
__global__ void hist_k(const int* __restrict__ dst, int* __restrict__ cnt) {
    int e = blockIdx.x * 256 + threadIdx.x;
    if (e < NE) atomicAdd(&cnt[dst[e]], 1);
}

__global__ void s1_k(const int* __restrict__ cnt, int* __restrict__ offs,
                     int* __restrict__ bsum) {
    __shared__ int sm[256];
    int t = threadIdx.x, b = blockIdx.x;
    int g = b * 256 + t;
    int v = (g < NN) ? cnt[g] : 0;
    sm[t] = v;
    __syncthreads();
    for (int o = 1; o < 256; o <<= 1) {
        int u = (t >= o) ? sm[t - o] : 0;
        __syncthreads();
        sm[t] += u;
        __syncthreads();
    }
    if (g < NN) offs[g + 1] = sm[t];
    if (t == 255) bsum[b] = sm[255];
}

__global__ void s2_k(int* __restrict__ bsum) {
    __shared__ int sm[512];
    int t = threadIdx.x;
    int v = (t < SCAN_B) ? bsum[t] : 0;
    sm[t] = v;
    __syncthreads();
    for (int o = 1; o < 512; o <<= 1) {
        int u = (t >= o) ? sm[t - o] : 0;
        __syncthreads();
        sm[t] += u;
        __syncthreads();
    }
    if (t < SCAN_B) bsum[t] = sm[t] - v;  // exclusive
}

__global__ void s3_k(int* __restrict__ offs, const int* __restrict__ bsum) {
    int t = threadIdx.x, b = blockIdx.x;
    int g = b * 256 + t;
    if (g < NN) offs[g + 1] += bsum[b];
    if (g == 0) offs[0] = 0;
}

__global__ void copyoff_k(const int* __restrict__ offs, int* __restrict__ cur) {
    int g = blockIdx.x * 256 + threadIdx.x;
    if (g < NN) cur[g] = offs[g];
}

__global__ void fill_k(const int* __restrict__ dst, int* __restrict__ cur,
                       int* __restrict__ perm) {
    int e = blockIdx.x * 256 + threadIdx.x;
    if (e < NE) {
        int pos = atomicAdd(&cur[dst[e]], 1);
        perm[pos] = e;
    }
}

// ---------------- MFMA y pipeline (unchanged from round 8) ----------------
// x (f32 [NN][32]) -> B-fragment-layout bf16
__global__ void castx_k(const float* __restrict__ in, bf16_t* __restrict__ outf) {
    int tid = blockIdx.x * 256 + threadIdx.x;  // (n, q): q = d-oct
    if (tid >= NN * 4) return;
    int n = tid >> 2, q = tid & 3;
    const float4* ip = (const float4*)(in + (long)n * DD + q * 8);
    float4 v0 = ip[0], v1 = ip[1];
    int tile = n >> 4;
    int lane = (n & 15) + 16 * q;
    unsigned* op = (unsigned*)(outf + ((long)tile * 64 + lane) * 8);
    op[0] = pk2(v0.x, v0.y);
    op[1] = pk2(v0.z, v0.w);
    op[2] = pk2(v1.x, v1.y);
    op[3] = pk2(v1.z, v1.w);
}

// W (f32 [K][32][32]) -> A-fragment-layout bf16
__global__ void castw_k(const float* __restrict__ W, bf16_t* __restrict__ wtf, int K) {
    int tid = blockIdx.x * 256 + threadIdx.x;
    if (tid >= K * 2 * 64) return;
    int l = tid & 63;
    int half = (tid >> 6) & 1;
    int k = tid >> 7;
    int e = (l & 15) + 16 * half;
    int dbase = (l >> 4) * 8;
    bf16_t* op = wtf + (long)tid * 8;
#pragma unroll
    for (int r = 0; r < 8; ++r)
        op[r] = f2bf(W[(long)k * 1024 + (dbase + r) * DD + e]);
}

template<int K>
__global__ __launch_bounds__(64) void ymm_k(const short8v* __restrict__ xtf,
                                            const short8v* __restrict__ wtf,
                                            unsigned* __restrict__ y) {
    constexpr int RS = K * 16 + 4;
    __shared__ unsigned lds[16 * RS];
    const int l = threadIdx.x;
    const int tile = blockIdx.x;
    const int node = l & 15, g = l >> 4;

    short8v b = xtf[(long)tile * 64 + l];
    float4v zz = {0.f, 0.f, 0.f, 0.f};

    for (int k = 0; k < K; ++k) {
        float4v d0 = __builtin_amdgcn_mfma_f32_16x16x32_bf16(wtf[(2 * k + 0) * 64 + l], b, zz, 0, 0, 0);
        float4v d1 = __builtin_amdgcn_mfma_f32_16x16x32_bf16(wtf[(2 * k + 1) * 64 + l], b, zz, 0, 0, 0);
        unsigned* lr = &lds[node * RS + k * 16];
        lr[2 * g]     = pk2(d0[0], d0[1]);
        lr[2 * g + 1] = pk2(d0[2], d0[3]);
        lr[8 + 2 * g]     = pk2(d1[0], d1[1]);
        lr[8 + 2 * g + 1] = pk2(d1[2], d1[3]);
    }
    __syncthreads();

    unsigned* yb = y + (long)tile * (16 * K * 16);
    constexpr int TOT = 16 * K * 16;
    for (int off = l * 4; off < TOT; off += 256) {
        int nd = off / (K * 16);
        int rem = off - nd * (K * 16);
        const unsigned* lp = &lds[nd * RS + rem];
        uint4 v = make_uint4(lp[0], lp[1], lp[2], lp[3]);
        *(uint4*)(yb + off) = v;
    }
}

// ---------------- dst-sorted edge phase ----------------
// per (sorted-edge j, e): 4-tap blend of gathered bf16 y rows, atomic scatter.
// Sorted order => ~deg(16) consecutive atomics per agg row => in-cache combine,
// one write-back per row; y stays L3-resident (no churn from atomic traffic).
template<int KS>
__global__ void edge_s_k(const int* __restrict__ perm, const int* __restrict__ src,
                         const int* __restrict__ dst, const float2* __restrict__ attr,
                         const bf16_t* __restrict__ y, float* __restrict__ agg) {
    long tid = (long)blockIdx.x * 256 + threadIdx.x;
    if (tid >= (long)NE * DD) return;
    int e = (int)(tid & (DD - 1));
    int j = (int)(tid >> 5);
    int ed = perm[j];               // group-uniform -> broadcast load
    const int K = KS * KS;
    float2 uv = attr[ed];
    int s = src[ed];
    int dn = dst[ed];
    float v0 = uv.x * (KS - 1), v1 = uv.y * (KS - 1);
    float fb0 = floorf(v0), fb1 = floorf(v1);
    float f0 = v0 - fb0, f1 = v1 - fb1;
    int i0 = min((int)fb0, KS - 1), i1 = min((int)fb1, KS - 1);
    int j0 = min(i0 + 1, KS - 1), j1 = min(i1 + 1, KS - 1);
    long base = (long)s * (K * DD) + e;
    float y00 = bf2f(y[base + (i0 + i1 * KS) * DD]);
    float y10 = bf2f(y[base + (j0 + i1 * KS) * DD]);
    float y01 = bf2f(y[base + (i0 + j1 * KS) * DD]);
    float y11 = bf2f(y[base + (j0 + j1 * KS) * DD]);
    float m = (1.f - f0) * (1.f - f1) * y00 + f0 * (1.f - f1) * y10
            + (1.f - f0) * f1 * y01 + f0 * f1 * y11;
    atomicAdd(&agg[(long)dn * DD + e], m);
}

// in-place finalize: agg[n,e] = elu(agg[n,e]/max(deg,1) + xin@root + bias)
__global__ __launch_bounds__(256) void fin_k(
        float* __restrict__ agg, const int* __restrict__ offs,
        const float* __restrict__ xin, const float* __restrict__ root,
        const float* __restrict__ bias) {
    const int lane = threadIdx.x & 31;
    const int grp = threadIdx.x >> 5;
    const int n = blockIdx.x * 8 + grp;
    if (n >= NN) return;
    int deg = offs[n + 1] - offs[n];
    float c = deg > 0 ? (float)deg : 1.f;
    float xv = xin[(long)n * DD + lane];
    float racc = 0.f;
#pragma unroll
    for (int d = 0; d < DD; ++d)
        racc = fmaf(__shfl(xv, d, 32), root[d * DD + lane], racc);
    float v = agg[(long)n * DD + lane] / c + racc + bias[lane];
    agg[(long)n * DD + lane] = v > 0.f ? v : expm1f(v);
}

// fused 2-layer MLP head
__global__ __launch_bounds__(256) void mlp_k(
        const float* __restrict__ h, const float* __restrict__ w1,
        const float* __restrict__ b1, const float* __restrict__ w2,
        const float* __restrict__ b2, float* __restrict__ out) {
    const int lane = threadIdx.x & 31;
    const int grp = threadIdx.x >> 5;
    const int n = blockIdx.x * 8 + grp;
    if (n >= NN) return;
    float hv = h[(long)n * DD + lane];
    float t = b1[lane];
#pragma unroll
    for (int d = 0; d < DD; ++d)
        t = fmaf(__shfl(hv, d, 32), w1[d * DD + lane], t);
    t = fmaxf(t, 0.f);
    int c = lane & (CC - 1);
    float o = 0.f;
#pragma unroll
    for (int d = 0; d < DD; ++d)
        o = fmaf(__shfl(t, d, 32), w2[d * CC + c], o);
    o += b2[c];
    o = fmaxf(o, 0.f);
    if (lane < CC) out[(long)n * CC + lane] = o;
}

extern "C" void kernel_launch(void* const* d_in, const int* in_sizes, int n_in,
                              void* d_out, int out_size, void* d_ws, size_t ws_size,
                              hipStream_t stream) {
    const float* x     = (const float*)d_in[0];
    const int*   ei    = (const int*)d_in[1];
    const float* attr  = (const float*)d_in[2];
    const float* W1    = (const float*)d_in[3];
    const float* root1 = (const float*)d_in[4];
    const float* bias1 = (const float*)d_in[5];
    const float* W2    = (const float*)d_in[6];
    const float* root2 = (const float*)d_in[7];
    const float* bias2 = (const float*)d_in[8];
    const float* m1w   = (const float*)d_in[9];
    const float* m1b   = (const float*)d_in[10];
    const float* m2w   = (const float*)d_in[11];
    const float* m2b   = (const float*)d_in[12];
    float* out = (float*)d_out;

    const int* srcp = ei;
    const int* dstp = ei + NE;

    // ws layout (aliased to fit):
    //   offs (NN+8 int) | perm (NE int) | aggA (NN*32 f32) | aggB (NN*32 f32)
    //   | wtf1 | wtf2 | y (NN*25*32 bf16)
    // aliases: cur,bsum inside aggA (CSR phase only); xtf inside aggB
    // (dead before aggB is zeroed); h1=aggA, h2=aggB (fin in-place).
    // total = 0.4 + 6.4 + 12.8 + 12.8 + 0.07 + 160 = 192.5 MB
    int* offs = (int*)d_ws;
    int* perm = offs + NN + 8;
    float* aggA = (float*)(perm + NE);
    float* aggB = aggA + (size_t)NN * DD;
    bf16_t* wtf1 = (bf16_t*)(aggB + (size_t)NN * DD);
    bf16_t* wtf2 = wtf1 + 9 * 2 * 64 * 8;
    bf16_t* y = wtf2 + 25 * 2 * 64 * 8;

    int* cur  = (int*)aggA;          // CSR-phase alias
    int* bsum = (int*)aggA + NN;     // CSR-phase alias
    bf16_t* xtf = (bf16_t*)aggB;     // pre-zero alias

    const unsigned gn = (NN + 7) / 8;
    const unsigned gt = NN / 16;  // 6250, exact

    // ---- CSR build (cur/bsum live in aggA) ----
    zero_int_k<<<gblocks(NN), 256, 0, stream>>>(cur, NN);
    hist_k<<<gblocks(NE), 256, 0, stream>>>(dstp, cur);
    s1_k<<<SCAN_B, 256, 0, stream>>>(cur, offs, bsum);
    s2_k<<<1, 512, 0, stream>>>(bsum);
    s3_k<<<SCAN_B, 256, 0, stream>>>(offs, bsum);
    copyoff_k<<<SCAN_B, 256, 0, stream>>>(offs, cur);
    fill_k<<<gblocks(NE), 256, 0, stream>>>(dstp, cur, perm);

    // ---- weight fragment packs ----
    castw_k<<<gblocks(9 * 2 * 64), 256, 0, stream>>>(W1, wtf1, 9);
    castw_k<<<gblocks(25 * 2 * 64), 256, 0, stream>>>(W2, wtf2, 25);

    // ---- layer 1 (ksize=3, K=9) ----
    castx_k<<<gblocks(NN * 4), 256, 0, stream>>>(x, xtf);
    ymm_k<9><<<gt, 64, 0, stream>>>((const short8v*)xtf, (const short8v*)wtf1, (unsigned*)y);
    zero_k<<<gblocks((long)NN * DD), 256, 0, stream>>>(aggA, (long)NN * DD);  // cur dead now
    edge_s_k<3><<<gblocks((long)NE * DD), 256, 0, stream>>>(perm, srcp, dstp, (const float2*)attr, y, aggA);
    fin_k<<<gn, 256, 0, stream>>>(aggA, offs, x, root1, bias1);   // aggA -> h1

    // ---- layer 2 (ksize=5, K=25) ----
    castx_k<<<gblocks(NN * 4), 256, 0, stream>>>(aggA, xtf);      // h1 -> fragments (in aggB)
    ymm_k<25><<<gt, 64, 0, stream>>>((const short8v*)xtf, (const short8v*)wtf2, (unsigned*)y);
    zero_k<<<gblocks((long)NN * DD), 256, 0, stream>>>(aggB, (long)NN * DD);  // xtf dead now
    edge_s_k<5><<<gblocks((long)NE * DD), 256, 0, stream>>>(perm, srcp, dstp, (const float2*)attr, y, aggB);
    fin_k<<<gn, 256, 0, stream>>>(aggB, offs, aggA, root2, bias2); // aggB -> h2

    // ---- fused MLP head ----
    mlp_k<<<gn, 256, 0, stream>>>(aggB, m1w, m1b, m2w, m2b, out);
}

// Round 10
// 949.357 us; speedup vs baseline: 1.4467x; 1.4467x over previous
//
#include <hip/hip_runtime.h>
#include <math.h>

#define NN 100000
#define NE 1600000
#define DD 32
#define CC 16
#define SCAN_B 391  // ceil(NN/256)

typedef unsigned short bf16_t;
typedef __attribute__((ext_vector_type(8))) short short8v;
typedef __attribute__((ext_vector_type(4))) float float4v;

static inline unsigned gblocks(long total) { return (unsigned)((total + 255) / 256); }

__device__ inline bf16_t f2bf(float f) {
    unsigned u = __float_as_uint(f);
    u += 0x7fffu + ((u >> 16) & 1u);
    return (bf16_t)(u >> 16);
}
__device__ inline float bf2f(bf16_t h) { return __uint_as_float(((unsigned)h) << 16); }
__device__ inline unsigned pk2(float a, float b) {
    return (unsigned)f2bf(a) | ((unsigned)f2bf(b) << 16);
}

__global__ void zero_int_k(int* p, int n) {
    int i = blockIdx.x * 256 + threadIdx.x;
    if (i < n) p[i] = 0;
}

// ---------------- CSR build ----------------
__global__ void hist_k(const int* __restrict__ dst, int* __restrict__ cnt) {
    int e = blockIdx.x * 256 + threadIdx.x;
    if (e < NE) atomicAdd(&cnt[dst[e]], 1);
}

__global__ void s1_k(const int* __restrict__ cnt, int* __restrict__ offs,
                     int* __restrict__ bsum) {
    __shared__ int sm[256];
    int t = threadIdx.x, b = blockIdx.x;
    int g = b * 256 + t;
    int v = (g < NN) ? cnt[g] : 0;
    sm[t] = v;
    __syncthreads();
    for (int o = 1; o < 256; o <<= 1) {
        int u = (t >= o) ? sm[t - o] : 0;
        __syncthreads();
        sm[t] += u;
        __syncthreads();
    }
    if (g < NN) offs[g + 1] = sm[t];
    if (t == 255) bsum[b] = sm[255];
}

__global__ void s2_k(int* __restrict__ bsum) {
    __shared__ int sm[512];
    int t = threadIdx.x;
    int v = (t < SCAN_B) ? bsum[t] : 0;
    sm[t] = v;
    __syncthreads();
    for (int o = 1; o < 512; o <<= 1) {
        int u = (t >= o) ? sm[t - o] : 0;
        __syncthreads();
        sm[t] += u;
        __syncthreads();
    }
    if (t < SCAN_B) bsum[t] = sm[t] - v;  // exclusive
}

__global__ void s3_k(int* __restrict__ offs, const int* __restrict__ bsum) {
    int t = threadIdx.x, b = blockIdx.x;
    int g = b * 256 + t;
    if (g < NN) offs[g + 1] += bsum[b];
    if (g == 0) offs[0] = 0;
}

__global__ void copyoff_k(const int* __restrict__ offs, int* __restrict__ cur) {
    int g = blockIdx.x * 256 + threadIdx.x;
    if (g < NN) cur[g] = offs[g];
}

// CSR fill + pre-gather into dst-sorted packed streams:
// epack = (src<<5) | (dst&31)   (dn valid since block n0 is a multiple of 32)
// eattrq = u0,u1 as 16-bit fixed point (error ~7.6e-6 -> ~1e-4 on messages)
__global__ void fill_k(const int* __restrict__ dst, const int* __restrict__ src,
                       const float2* __restrict__ attr, int* __restrict__ cur,
                       int* __restrict__ epack, unsigned* __restrict__ eattrq) {
    int e = blockIdx.x * 256 + threadIdx.x;
    if (e < NE) {
        int d = dst[e];
        int pos = atomicAdd(&cur[d], 1);
        epack[pos] = (src[e] << 5) | (d & 31);
        float2 uv = attr[e];
        unsigned q0 = (unsigned)(uv.x * 65535.f + 0.5f);
        unsigned q1 = (unsigned)(uv.y * 65535.f + 0.5f);
        eattrq[pos] = q0 | (q1 << 16);
    }
}

// ---------------- MFMA y pipeline (proven round 8) ----------------
__global__ void castx_k(const float* __restrict__ in, bf16_t* __restrict__ outf) {
    int tid = blockIdx.x * 256 + threadIdx.x;  // (n, q): q = d-oct
    if (tid >= NN * 4) return;
    int n = tid >> 2, q = tid & 3;
    const float4* ip = (const float4*)(in + (long)n * DD + q * 8);
    float4 v0 = ip[0], v1 = ip[1];
    int tile = n >> 4;
    int lane = (n & 15) + 16 * q;
    unsigned* op = (unsigned*)(outf + ((long)tile * 64 + lane) * 8);
    op[0] = pk2(v0.x, v0.y);
    op[1] = pk2(v0.z, v0.w);
    op[2] = pk2(v1.x, v1.y);
    op[3] = pk2(v1.z, v1.w);
}

__global__ void castw_k(const float* __restrict__ W, bf16_t* __restrict__ wtf, int K) {
    int tid = blockIdx.x * 256 + threadIdx.x;
    if (tid >= K * 2 * 64) return;
    int l = tid & 63;
    int half = (tid >> 6) & 1;
    int k = tid >> 7;
    int e = (l & 15) + 16 * half;
    int dbase = (l >> 4) * 8;
    bf16_t* op = wtf + (long)tid * 8;
#pragma unroll
    for (int r = 0; r < 8; ++r)
        op[r] = f2bf(W[(long)k * 1024 + (dbase + r) * DD + e]);
}

template<int K>
__global__ __launch_bounds__(64) void ymm_k(const short8v* __restrict__ xtf,
                                            const short8v* __restrict__ wtf,
                                            unsigned* __restrict__ y) {
    constexpr int RS = K * 16 + 4;
    __shared__ unsigned lds[16 * RS];
    const int l = threadIdx.x;
    const int tile = blockIdx.x;
    const int node = l & 15, g = l >> 4;

    short8v b = xtf[(long)tile * 64 + l];
    float4v zz = {0.f, 0.f, 0.f, 0.f};

    for (int k = 0; k < K; ++k) {
        float4v d0 = __builtin_amdgcn_mfma_f32_16x16x32_bf16(wtf[(2 * k + 0) * 64 + l], b, zz, 0, 0, 0);
        float4v d1 = __builtin_amdgcn_mfma_f32_16x16x32_bf16(wtf[(2 * k + 1) * 64 + l], b, zz, 0, 0, 0);
        unsigned* lr = &lds[node * RS + k * 16];
        lr[2 * g]     = pk2(d0[0], d0[1]);
        lr[2 * g + 1] = pk2(d0[2], d0[3]);
        lr[8 + 2 * g]     = pk2(d1[0], d1[1]);
        lr[8 + 2 * g + 1] = pk2(d1[2], d1[3]);
    }
    __syncthreads();

    unsigned* yb = y + (long)tile * (16 * K * 16);
    constexpr int TOT = 16 * K * 16;
    for (int off = l * 4; off < TOT; off += 256) {
        int nd = off / (K * 16);
        int rem = off - nd * (K * 16);
        const unsigned* lp = &lds[nd * RS + rem];
        uint4 v = make_uint4(lp[0], lp[1], lp[2], lp[3]);
        *(uint4*)(yb + off) = v;
    }
}

// ---------------- fused edge aggregation + finalize ----------------
// Block = 32 consecutive dst nodes (exclusive ownership). Edges of these
// nodes form ONE contiguous sorted range -> metadata reads are sequential
// streams. Messages accumulate via LDS atomics (zero global atomic traffic);
// finalize (mean + root matvec + bias + ELU) fused, plain coalesced stores.
template<int KS>
__global__ __launch_bounds__(256) void edge_agg_k(
        const int* __restrict__ offs, const int* __restrict__ epack,
        const unsigned* __restrict__ eattrq, const bf16_t* __restrict__ y,
        const float* __restrict__ xin, const float* __restrict__ root,
        const float* __restrict__ bias, float* __restrict__ hout) {
    constexpr int K = KS * KS;
    __shared__ float accs[32 * 33];
    __shared__ int offl[33];
    const int tid = threadIdx.x;
    const int n0 = blockIdx.x * 32;
    if (tid < 33) offl[tid] = offs[n0 + tid <= NN ? n0 + tid : NN];
    for (int i = tid; i < 32 * 33; i += 256) accs[i] = 0.f;
    __syncthreads();

    const int lane = tid & 31, g = tid >> 5;
    const int j0 = offl[0], j1 = offl[32];
    for (int j = j0 + g; j < j1; j += 8) {
        int pk = epack[j];          // sequential stream, broadcast in group
        unsigned aq = eattrq[j];
        int s = pk >> 5;
        int dn = pk & 31;
        float u0 = (float)(aq & 0xffffu) * (1.f / 65535.f);
        float u1 = (float)(aq >> 16) * (1.f / 65535.f);
        float v0 = u0 * (KS - 1), v1 = u1 * (KS - 1);
        float fb0 = floorf(v0), fb1 = floorf(v1);
        float f0 = v0 - fb0, f1 = v1 - fb1;
        int i0 = min((int)fb0, KS - 1), i1 = min((int)fb1, KS - 1);
        int q0 = min(i0 + 1, KS - 1), q1 = min(i1 + 1, KS - 1);
        const bf16_t* yb = y + (long)s * (K * DD) + lane;
        float y00 = bf2f(yb[(i0 + i1 * KS) * DD]);
        float y10 = bf2f(yb[(q0 + i1 * KS) * DD]);
        float y01 = bf2f(yb[(i0 + q1 * KS) * DD]);
        float y11 = bf2f(yb[(q0 + q1 * KS) * DD]);
        float m = (1.f - f0) * (1.f - f1) * y00 + f0 * (1.f - f1) * y10
                + (1.f - f0) * f1 * y01 + f0 * f1 * y11;
        atomicAdd(&accs[dn * 33 + lane], m);   // LDS atomic, bank-clean
    }
    __syncthreads();

    // finalize: 8 groups x 4 nodes
#pragma unroll
    for (int i = 0; i < 4; ++i) {
        int ln = g + 8 * i;
        int n = n0 + ln;
        if (n >= NN) continue;
        int deg = offl[ln + 1] - offl[ln];
        float c = deg > 0 ? (float)deg : 1.f;
        float xv = xin[(long)n * DD + lane];
        float racc = 0.f;
#pragma unroll
        for (int d = 0; d < DD; ++d)
            racc = fmaf(__shfl(xv, d, 32), root[d * DD + lane], racc);
        float v = accs[ln * 33 + lane] / c + racc + bias[lane];
        hout[(long)n * DD + lane] = v > 0.f ? v : expm1f(v);
    }
}

// fused 2-layer MLP head
__global__ __launch_bounds__(256) void mlp_k(
        const float* __restrict__ h, const float* __restrict__ w1,
        const float* __restrict__ b1, const float* __restrict__ w2,
        const float* __restrict__ b2, float* __restrict__ out) {
    const int lane = threadIdx.x & 31;
    const int grp = threadIdx.x >> 5;
    const int n = blockIdx.x * 8 + grp;
    if (n >= NN) return;
    float hv = h[(long)n * DD + lane];
    float t = b1[lane];
#pragma unroll
    for (int d = 0; d < DD; ++d)
        t = fmaf(__shfl(hv, d, 32), w1[d * DD + lane], t);
    t = fmaxf(t, 0.f);
    int c = lane & (CC - 1);
    float o = 0.f;
#pragma unroll
    for (int d = 0; d < DD; ++d)
        o = fmaf(__shfl(t, d, 32), w2[d * CC + c], o);
    o += b2[c];
    o = fmaxf(o, 0.f);
    if (lane < CC) out[(long)n * CC + lane] = o;
}

extern "C" void kernel_launch(void* const* d_in, const int* in_sizes, int n_in,
                              void* d_out, int out_size, void* d_ws, size_t ws_size,
                              hipStream_t stream) {
    const float* x     = (const float*)d_in[0];
    const int*   ei    = (const int*)d_in[1];
    const float* attr  = (const float*)d_in[2];
    const float* W1    = (const float*)d_in[3];
    const float* root1 = (const float*)d_in[4];
    const float* bias1 = (const float*)d_in[5];
    const float* W2    = (const float*)d_in[6];
    const float* root2 = (const float*)d_in[7];
    const float* bias2 = (const float*)d_in[8];
    const float* m1w   = (const float*)d_in[9];
    const float* m1b   = (const float*)d_in[10];
    const float* m2w   = (const float*)d_in[11];
    const float* m2b   = (const float*)d_in[12];
    float* out = (float*)d_out;

    const int* srcp = ei;
    const int* dstp = ei + NE;

    // ws: offs(NN+8 int) | epack(NE int) | eattrq(NE u32) | xtf(NN*32 bf16)
    //     | wtf1 | wtf2 | y(NN*25*32 bf16) | h1(NN*32 f32)
    // cur/bsum alias h1 (CSR phase only; h1 first written by edge_agg<3>).
    // total = 0.4 + 6.4 + 6.4 + 6.4 + 0.07 + 160 + 12.8 = 192.5 MB
    int* offs = (int*)d_ws;
    int* epack = offs + NN + 8;
    unsigned* eattrq = (unsigned*)(epack + NE);
    bf16_t* xtf = (bf16_t*)(eattrq + NE);
    bf16_t* wtf1 = xtf + (size_t)NN * DD;
    bf16_t* wtf2 = wtf1 + 9 * 2 * 64 * 8;
    bf16_t* y = wtf2 + 25 * 2 * 64 * 8;
    float* h1 = (float*)(y + (size_t)NN * 25 * DD);
    int* cur  = (int*)h1;
    int* bsum = (int*)h1 + NN;

    const unsigned gn = (NN + 7) / 8;
    const unsigned gt = NN / 16;    // 6250 exact
    const unsigned ga = NN / 32;    // 3125 exact

    // ---- CSR build + packed pre-gather ----
    zero_int_k<<<gblocks(NN), 256, 0, stream>>>(cur, NN);
    hist_k<<<gblocks(NE), 256, 0, stream>>>(dstp, cur);
    s1_k<<<SCAN_B, 256, 0, stream>>>(cur, offs, bsum);
    s2_k<<<1, 512, 0, stream>>>(bsum);
    s3_k<<<SCAN_B, 256, 0, stream>>>(offs, bsum);
    copyoff_k<<<SCAN_B, 256, 0, stream>>>(offs, cur);
    fill_k<<<gblocks(NE), 256, 0, stream>>>(dstp, srcp, (const float2*)attr, cur, epack, eattrq);

    // ---- weight fragment packs ----
    castw_k<<<gblocks(9 * 2 * 64), 256, 0, stream>>>(W1, wtf1, 9);
    castw_k<<<gblocks(25 * 2 * 64), 256, 0, stream>>>(W2, wtf2, 25);

    // ---- layer 1 (ksize=3, K=9) ----
    castx_k<<<gblocks(NN * 4), 256, 0, stream>>>(x, xtf);
    ymm_k<9><<<gt, 64, 0, stream>>>((const short8v*)xtf, (const short8v*)wtf1, (unsigned*)y);
    edge_agg_k<3><<<ga, 256, 0, stream>>>(offs, epack, eattrq, y, x, root1, bias1, h1);

    // ---- layer 2 (ksize=5, K=25) ----
    castx_k<<<gblocks(NN * 4), 256, 0, stream>>>(h1, xtf);
    ymm_k<25><<<gt, 64, 0, stream>>>((const short8v*)xtf, (const short8v*)wtf2, (unsigned*)y);
    edge_agg_k<5><<<ga, 256, 0, stream>>>(offs, epack, eattrq, y, h1, root2, bias2, h1);  // in-place

    // ---- fused MLP head ----
    mlp_k<<<gn, 256, 0, stream>>>(h1, m1w, m1b, m2w, m2b, out);
}